// Round 4
// baseline (501.316 us; speedup 1.0000x reference)
//
#include <hip/hip_runtime.h>
#include <math.h>

#define NB 4096
#define NR 49
#define NS 50
#define ND 512
#define NK 100
#define NT 7           // N-tiles of 16 cols (112 >= 100)
#define KSTEPS 16      // 512 / 32
#define FRAGS (NT * KSTEPS * 64 * 8)   // 57344 ushorts (114688 B) per weight matrix

typedef __attribute__((ext_vector_type(8))) short short8;
typedef __attribute__((ext_vector_type(4))) float f32x4;

__device__ __forceinline__ unsigned short f32_bf16(float f) {
    union { float f; unsigned u; } x; x.f = f;
    return (unsigned short)((x.u + 0x7fffu + ((x.u >> 16) & 1u)) >> 16);  // RNE
}
__device__ __forceinline__ float bf16_f32(unsigned short h) {
    union { unsigned u; float f; } x; x.u = ((unsigned)h) << 16;
    return x.f;
}
__device__ __forceinline__ unsigned cvt_pk_bf16(float lo, float hi) {
    unsigned r;
    asm("v_cvt_pk_bf16_f32 %0, %1, %2" : "=v"(r) : "v"(lo), "v"(hi));
    return r;  // low 16 = bf16(lo), high 16 = bf16(hi)
}
__device__ __forceinline__ float fast_tanh(float x) {
    const float ax = fabsf(x);
    const float e = __expf(2.f * ax);            // inf for large ax -> r = 1
    const float r = 1.f - 2.f / (e + 1.f);
    return copysignf(r, x);
}

// ---------------------------------------------------------------------------
// Pre-pass: 2 weight matrices [512][100] f32 -> bf16 MFMA B-fragments.
// (Only w_Vi_0 and w_Vt_1 are needed: the broadcast conditioning branches
//  are constant along the softmax axis and cancel exactly.)
// frag(t, ks): lane l holds W[k = ks*32 + (l>>4)*8 + j][col = t*16 + (l&15)].
// ---------------------------------------------------------------------------
__global__ void preswz_kernel(const float* __restrict__ w0, const float* __restrict__ w1,
                              unsigned short* __restrict__ ws)
{
    const int l  = threadIdx.x;          // 64
    const int ks = blockIdx.x & 15;
    const int t  = blockIdx.x >> 4;      // 0..6
    const int m  = blockIdx.y;           // 0..1
    const float* W = m ? w1 : w0;
    const int col = t * 16 + (l & 15);
    const int k0  = ks * 32 + (l >> 4) * 8;
    unsigned short* o = ws + (size_t)m * FRAGS + ((size_t)(t * 16 + ks) * 64 + l) * 8;
#pragma unroll
    for (int j = 0; j < 8; ++j) {
        float v = (col < NK) ? W[(size_t)(k0 + j) * NK + col] : 0.f;
        o[j] = f32_bf16(v);
    }
}

// ---------------------------------------------------------------------------
// Main kernel: one block per batch, 512 threads (8 waves).
// ---------------------------------------------------------------------------
struct SM {
    short buf[NS * ND];      // 51200 B: bf16 feature tile (I, then reused for T)
    float scores[64];        // row partials n-half 0 (incl. bias)
    float part2[64];         // row partials n-half 1
    float P[64];
    float vibuf[ND];         // attended image feature (f32)
};

// Rows-GEMM score pass: A[64x512](LDS bf16) x Wrow[512x112](L2 bf16 frags),
// epilogue s[row] = sum_col tanh(D)*wPiRow[col] (+bias).
// Wave (m = wid&3) owns rows 16m..16m+15; n-half (wid>>2) owns tiles t0..t0+tcnt-1.
__device__ __forceinline__ void score_pass(
    const short* __restrict__ At, const unsigned short* __restrict__ wsR,
    const float* __restrict__ wPiRow, const float* __restrict__ bvec,
    int nrows, int nclamp,
    float* __restrict__ outA, float* __restrict__ outB, int tid)
{
    const int lane = tid & 63, wid = tid >> 6;
    const int m = wid & 3, nh = wid >> 2;
    const int t0 = nh * 4, tcnt = nh ? 3 : 4;
    const int colg = lane & 15, g = lane >> 4;
    const int arow0 = m * 16 + colg;
    const int arow = (arow0 < nclamp) ? arow0 : nclamp;   // clamp padded rows
    const int rswz = arow & 7;

    const unsigned short* wbase[4];
#pragma unroll
    for (int q = 0; q < 4; ++q)
        wbase[q] = wsR + (size_t)(t0 + q) * (KSTEPS * 512) + lane * 8;

    const f32x4 zero4 = {0.f, 0.f, 0.f, 0.f};
    f32x4 acc[4] = {zero4, zero4, zero4, zero4};

    short8 wf[2][4];   // depth-2 weight prefetch (static rotation under full unroll)
#pragma unroll
    for (int s = 0; s < 2; ++s)
#pragma unroll
        for (int q = 0; q < 4; ++q)
            if (q < tcnt) wf[s][q] = *reinterpret_cast<const short8*>(wbase[q] + s * 512);

#pragma unroll
    for (int ks = 0; ks < KSTEPS; ++ks) {
        const short8 a = *reinterpret_cast<const short8*>(
            &At[arow * 512 + (((ks * 4 + g) ^ rswz) << 3)]);
        short8 cur[4];
#pragma unroll
        for (int q = 0; q < 4; ++q) cur[q] = wf[ks & 1][q];
        if (ks + 2 < KSTEPS) {
#pragma unroll
            for (int q = 0; q < 4; ++q)
                if (q < tcnt) wf[ks & 1][q] = *reinterpret_cast<const short8*>(wbase[q] + (ks + 2) * 512);
        }
#pragma unroll
        for (int q = 0; q < 4; ++q)
            if (q < tcnt) acc[q] = __builtin_amdgcn_mfma_f32_16x16x32_bf16(a, cur[q], acc[q], 0, 0, 0);
    }

    // epilogue: s[row] = sum_cols tanh(D) * wPiRow; shfl-reduce 16 col-lanes
    float s[4] = {0.f, 0.f, 0.f, 0.f};
#pragma unroll
    for (int q = 0; q < 4; ++q)
        if (q < tcnt) {
            const int col = (t0 + q) * 16 + colg;
            const float w = (col < NK) ? wPiRow[col] : 0.f;
#pragma unroll
            for (int i = 0; i < 4; ++i) s[i] += fast_tanh(acc[q][i]) * w;
        }
#pragma unroll
    for (int off = 1; off < 16; off <<= 1) {
#pragma unroll
        for (int i = 0; i < 4; ++i) s[i] += __shfl_xor(s[i], off);
    }
    if (colg == 0) {
        float* o = nh ? outB : outA;
        const int rbase = m * 16 + g * 4;
#pragma unroll
        for (int i = 0; i < 4; ++i) {
            const int r = rbase + i;
            if (r < nrows) o[r] = s[i] + (nh ? 0.f : bvec[r]);
        }
    }
}

__global__ __launch_bounds__(512, 6) void coattn_main(
    const float* __restrict__ ifeat, const float* __restrict__ tfeat,
    const float* __restrict__ wPi0, const float* __restrict__ bPi0,
    const float* __restrict__ wPi1, const float* __restrict__ bPi1,
    const unsigned short* __restrict__ wsW, float* __restrict__ out)
{
    __shared__ SM sm;
    const int b = blockIdx.x, tid = threadIdx.x;
    const float* ig = ifeat + (size_t)b * NR * ND;
    const float* tg = tfeat + (size_t)b * NS * ND;

    // ---- stage I -> LDS (bf16, 16B-chunk XOR swizzle); T -> registers
    for (int ci = tid; ci < NR * 64; ci += 512) {
        const int row = ci >> 6, c = ci & 63;
        const float* p = ig + (row << 9) + (c << 3);
        const float4 a  = *reinterpret_cast<const float4*>(p);
        const float4 b4 = *reinterpret_cast<const float4*>(p + 4);
        uint4 v;
        v.x = cvt_pk_bf16(a.x, a.y);   v.y = cvt_pk_bf16(a.z, a.w);
        v.z = cvt_pk_bf16(b4.x, b4.y); v.w = cvt_pk_bf16(b4.z, b4.w);
        *reinterpret_cast<uint4*>(&sm.buf[(row << 9) + ((c ^ (row & 7)) << 3)]) = v;
    }
    unsigned treg[25];      // T[0..49][tid] as packed bf16 pairs (rows 2j, 2j+1)
    {
        const float* tp = tg + tid;
#pragma unroll
        for (int j = 0; j < 25; ++j)
            treg[j] = cvt_pk_bf16(tp[(2 * j) * ND], tp[(2 * j + 1) * ND]);
    }
    __syncthreads();

    // ---- pass 0: scores_i (conditioning branch cancels in softmax)
    score_pass(sm.buf, wsW, wPi0, bPi0, NR, NR - 1, sm.scores, sm.part2, tid);
    __syncthreads();

    if (tid < 64) {   // softmax over R
        const float v = (tid < NR) ? sm.scores[tid] + sm.part2[tid] : -3.0e38f;
        float mx = v;
#pragma unroll
        for (int off = 32; off; off >>= 1) mx = fmaxf(mx, __shfl_xor(mx, off));
        const float e = (tid < NR) ? __expf(v - mx) : 0.f;
        float su = e;
#pragma unroll
        for (int off = 32; off; off >>= 1) su += __shfl_xor(su, off);
        sm.P[tid] = e / su;
    }
    __syncthreads();

    // ---- phase F: vi = sum_r P[r] * I[r,:]  (256 threads x 2 cols, b32 reads)
    if (tid < 256) {
        const int ch = tid >> 2, lo2 = (tid & 3) * 2;   // cols 2*tid, 2*tid+1
        float vx = 0.f, vy = 0.f;
        for (int r = 0; r < NR; ++r) {
            const float p = sm.P[r];
            const unsigned u = *reinterpret_cast<const unsigned*>(
                &sm.buf[r * 512 + ((ch ^ (r & 7)) << 3) + lo2]);
            vx += p * bf16_f32((unsigned short)(u & 0xffffu));
            vy += p * bf16_f32((unsigned short)(u >> 16));
        }
        sm.vibuf[2 * tid]     = vx;
        sm.vibuf[2 * tid + 1] = vy;
    }
    __syncthreads();   // I-LDS reads complete before overwrite

    // ---- dump T regs -> LDS (same swizzle)
    {
        const int ch = tid >> 3, lo = tid & 7;
#pragma unroll
        for (int j = 0; j < 25; ++j) {
            const unsigned u = treg[j];
            const int r0 = 2 * j, r1 = 2 * j + 1;
            sm.buf[r0 * 512 + ((ch ^ (r0 & 7)) << 3) + lo] = (short)(u & 0xffffu);
            sm.buf[r1 * 512 + ((ch ^ (r1 & 7)) << 3) + lo] = (short)(u >> 16);
        }
    }
    __syncthreads();

    // ---- pass 1: scores_t (conditioning branch cancels in softmax)
    score_pass(sm.buf, wsW + (size_t)FRAGS, wPi1 + NK, bPi1, NS, NS - 1,
               sm.scores, sm.part2, tid);
    __syncthreads();

    if (tid < 64) {   // softmax over S
        const float v = (tid < NS) ? sm.scores[tid] + sm.part2[tid] : -3.0e38f;
        float mx = v;
#pragma unroll
        for (int off = 32; off; off >>= 1) mx = fmaxf(mx, __shfl_xor(mx, off));
        const float e = (tid < NS) ? __expf(v - mx) : 0.f;
        float su = e;
#pragma unroll
        for (int off = 32; off; off >>= 1) su += __shfl_xor(su, off);
        sm.P[tid] = e / su;
    }
    __syncthreads();

    // ---- phase J: out[tid] = vi[tid] + sum_s P[s] * T[s, tid]   (pure registers)
    {
        float o = sm.vibuf[tid];
#pragma unroll
        for (int j = 0; j < 25; ++j) {
            const unsigned u = treg[j];
            o += sm.P[2 * j]     * bf16_f32((unsigned short)(u & 0xffffu));
            o += sm.P[2 * j + 1] * bf16_f32((unsigned short)(u >> 16));
        }
        out[(size_t)b * ND + tid] = o;
    }
}

extern "C" void kernel_launch(void* const* d_in, const int* in_sizes, int n_in,
                              void* d_out, int out_size, void* d_ws, size_t ws_size,
                              hipStream_t stream) {
    const float* ifeat = (const float*)d_in[0];
    const float* tfeat = (const float*)d_in[1];
    const float* wVi0  = (const float*)d_in[2];
    const float* wPi0  = (const float*)d_in[4];
    const float* bPi0  = (const float*)d_in[5];
    const float* wVt1  = (const float*)d_in[7];
    const float* wPi1  = (const float*)d_in[8];
    const float* bPi1  = (const float*)d_in[9];
    float* outp = (float*)d_out;
    unsigned short* wsW = (unsigned short*)d_ws;   // 2*114688 = 229376 B

    hipLaunchKernelGGL(preswz_kernel, dim3(NT * KSTEPS, 2), dim3(64), 0, stream,
                       wVi0, wVt1, wsW);
    hipLaunchKernelGGL(coattn_main, dim3(NB), dim3(512), 0, stream,
                       ifeat, tfeat, wPi0, bPi0, wPi1, bPi1, wsW, outp);
}